// Round 2
// baseline (223.612 us; speedup 1.0000x reference)
//
#include <hip/hip_runtime.h>

#define NROWS 4096
#define DCOLS 4096
#define MARGIN 1.2f

// One block (256 threads) per row.
// loss_i = y_i * d2 + (1-y_i) * max(0, MARGIN - sqrt(d2)),  d2 = ||x0_i - x1_i||^2
// Each block atomically adds loss_i / (2N) into out[0].
__global__ __launch_bounds__(256) void row_loss_kernel(
    const float* __restrict__ x0, const float* __restrict__ x1,
    const int* __restrict__ y, float* __restrict__ out) {
    const int row = blockIdx.x;
    const float4* __restrict__ a = (const float4*)(x0 + (size_t)row * DCOLS);
    const float4* __restrict__ b = (const float4*)(x1 + (size_t)row * DCOLS);
    const int t = threadIdx.x;

    // 1024 float4 per row / 256 threads = 4 per thread. Explicit independent
    // loads so all 8 global_load_dwordx4 are in flight simultaneously
    // (VGPR=8 last round => serialized load->wait->fma, latency-bound).
    float4 va0 = a[t];
    float4 va1 = a[t + 256];
    float4 va2 = a[t + 512];
    float4 va3 = a[t + 768];
    float4 vb0 = b[t];
    float4 vb1 = b[t + 256];
    float4 vb2 = b[t + 512];
    float4 vb3 = b[t + 768];

    float s0 = 0.f, s1 = 0.f, s2 = 0.f, s3 = 0.f;
    float d;
    d = va0.x - vb0.x; s0 = fmaf(d, d, s0);
    d = va0.y - vb0.y; s1 = fmaf(d, d, s1);
    d = va0.z - vb0.z; s2 = fmaf(d, d, s2);
    d = va0.w - vb0.w; s3 = fmaf(d, d, s3);
    d = va1.x - vb1.x; s0 = fmaf(d, d, s0);
    d = va1.y - vb1.y; s1 = fmaf(d, d, s1);
    d = va1.z - vb1.z; s2 = fmaf(d, d, s2);
    d = va1.w - vb1.w; s3 = fmaf(d, d, s3);
    d = va2.x - vb2.x; s0 = fmaf(d, d, s0);
    d = va2.y - vb2.y; s1 = fmaf(d, d, s1);
    d = va2.z - vb2.z; s2 = fmaf(d, d, s2);
    d = va2.w - vb2.w; s3 = fmaf(d, d, s3);
    d = va3.x - vb3.x; s0 = fmaf(d, d, s0);
    d = va3.y - vb3.y; s1 = fmaf(d, d, s1);
    d = va3.z - vb3.z; s2 = fmaf(d, d, s2);
    d = va3.w - vb3.w; s3 = fmaf(d, d, s3);
    float s = (s0 + s1) + (s2 + s3);

    // wave64 reduction
    #pragma unroll
    for (int off = 32; off > 0; off >>= 1) s += __shfl_down(s, off, 64);

    __shared__ float smem[4];
    const int lane = t & 63;
    const int wid = t >> 6;
    if (lane == 0) smem[wid] = s;
    __syncthreads();

    if (t == 0) {
        float d2 = (smem[0] + smem[1]) + (smem[2] + smem[3]);
        float dist = sqrtf(d2);
        float clamped = fmaxf(MARGIN - dist, 0.f);
        float yf = (float)y[row];
        float loss = yf * d2 + (1.f - yf) * clamped;
        atomicAdd(out, loss * (1.f / (2.f * (float)NROWS)));
    }
}

extern "C" void kernel_launch(void* const* d_in, const int* in_sizes, int n_in,
                              void* d_out, int out_size, void* d_ws, size_t ws_size,
                              hipStream_t stream) {
    const float* x0 = (const float*)d_in[0];
    const float* x1 = (const float*)d_in[1];
    // d_in[2], d_in[3] (x_c_0, x_c_1) are dead in the reference computation.
    const int* y = (const int*)d_in[4];
    float* out = (float*)d_out;

    // d_out is poisoned 0xAA before every launch — zero it (memset node is
    // graph-capture legal), then accumulate atomically from each row-block.
    hipMemsetAsync(out, 0, (size_t)out_size * sizeof(float), stream);
    row_loss_kernel<<<NROWS, 256, 0, stream>>>(x0, x1, y, out);
}